// Round 5
// baseline (1882.132 us; speedup 1.0000x reference)
//
#include <hip/hip_runtime.h>
#include <hip/hip_bf16.h>

// Problem: H=256, N=200000 sessions, U=20000 users.
// Runtime-detects whether float tensors are f32 or bf16, and whether
// user_ids is int64 or int32. Output dtype follows the float dtype.
#define HDIM 256
#define NROWS 200000
#define NUSERS 20000

// Harness-boilerplate symbol (defined, unused).
__global__ void UserSessionSimNet_21345987461278_kernel() {}

__device__ __forceinline__ float b2f(__hip_bfloat16 v) { return __bfloat162float(v); }

// Dual-dtype load: f32m!=0 -> float buffer, else bf16 buffer.
__device__ __forceinline__ float ldx(const void* p, int idx, int f32m) {
  if (f32m != 0) return ((const float*)p)[idx];
  return b2f(((const __hip_bfloat16*)p)[idx]);
}

// flags[0]=uid-is-int32, flags[1]=bf16 vote count, flags[2]=f32 mode
// ---- init ------------------------------------------------------------------
__global__ void k_init(int* counts, int* cursor, float* denom, int* segmaxB, int* flags) {
  int i = blockIdx.x * 256 + threadIdx.x;
  if (i < 3) flags[i] = 0;
  if (i < NUSERS) {
    counts[i] = 0;
    cursor[i] = 0;
    denom[i] = 0.0f;
    segmaxB[i] = (int)0xFF800000;  // -inf
  }
}

// ---- float dtype vote: bits[14:7] of each 32-bit word -----------------------
// bf16-pair data: that field is a bf16 exponent -> concentrated near 127.
// f32 data: that field is low mantissa bits -> ~uniform.
__global__ void k_dtype(const unsigned int* words, int* flags) {
  int i = blockIdx.x * 256 + threadIdx.x;  // 0..1023
  unsigned int f = (words[i] >> 7) & 0xFFu;
  if (f >= 100u && f <= 140u) atomicAdd(&flags[1], 1);
}

__global__ void k_flagfin(int* flags) {
  if (threadIdx.x == 0 && blockIdx.x == 0) {
    flags[2] = (flags[1] < 512) ? 1 : 0;  // few exponent-like hits -> f32
  }
}

// ---- user_ids dtype detect + convert ---------------------------------------
// int64 (LE): high word of every element is 0 (uids < 20000).
__global__ void k_detect(const int* raw, int* flags) {
  int i = blockIdx.x * 256 + threadIdx.x;  // 0..1023
  if (raw[2 * i + 1] != 0) atomicOr(&flags[0], 1);
}

__global__ void k_cvt(const int* raw, const int* flags, int* uid32) {
  int i = blockIdx.x * 256 + threadIdx.x;
  if (i >= NROWS) return;
  if (flags[0] != 0) {
    uid32[i] = raw[i];      // int32 data
  } else {
    uid32[i] = raw[2 * i];  // int64 data: low word
  }
}

// ---- pack: M = Wq*Wk^T, P = Wv*W1a^T, W1bT[k][n] = W1[n][256+k] (all f32) --
__global__ void k_pack(const void* Wq, const void* Wk, const void* Wv, const void* W1,
                       const int* flags, float* pM, float* pP, float* pW1bT) {
  int a = blockIdx.x;   // k index
  int j = threadIdx.x;  // n index
  int f32m = flags[2];
  float accM = 0.0f, accP = 0.0f;
  for (int c = 0; c < HDIM; ++c) {
    float wq = ldx(Wq, a * HDIM + c, f32m);
    float wv = ldx(Wv, a * HDIM + c, f32m);
    float wk = ldx(Wk, j * HDIM + c, f32m);
    float w1 = ldx(W1, j * 2 * HDIM + c, f32m);
    accM += wq * wk;
    accP += wv * w1;
  }
  pM[a * HDIM + j] = accM;
  pP[a * HDIM + j] = accP;
  pW1bT[a * HDIM + j] = ldx(W1, j * 2 * HDIM + HDIM + a, f32m);
}

// ---- CSR build -------------------------------------------------------------
__global__ void k_hist(const int* uid, int* counts) {
  int i = blockIdx.x * 256 + threadIdx.x;
  if (i < NROWS) atomicAdd(&counts[uid[i]], 1);
}

__global__ void k_scan(const int* counts, int* offs) {
  __shared__ int partial[256];
  int t = threadIdx.x;
  const int CH = (NUSERS + 255) / 256;  // 79
  int s = 0;
  for (int k = 0; k < CH; ++k) {
    int i = t * CH + k;
    if (i < NUSERS) s += counts[i];
  }
  partial[t] = s;
  __syncthreads();
  if (t == 0) {
    int run = 0;
    for (int k = 0; k < 256; ++k) { int v = partial[k]; partial[k] = run; run += v; }
  }
  __syncthreads();
  int run = partial[t];
  for (int k = 0; k < CH; ++k) {
    int i = t * CH + k;
    if (i < NUSERS) { offs[i] = run; run += counts[i]; }
  }
}

__global__ void k_scatter(const int* uid, const int* offs, int* cursor, int* rows) {
  int i = blockIdx.x * 256 + threadIdx.x;
  if (i < NROWS) {
    int u = uid[i];
    int p = offs[u] + atomicAdd(&cursor[u], 1);
    rows[p] = i;
  }
}

// ---- GEMM core: 16 rows/block, 256 threads (thread = output column) --------
// acc[r] = sum_k A[rowBase+r][k] * B[k][tid];  A dual-dtype, B f32.
__device__ __forceinline__ void gemm_core(const void* A, const float* B, int f32m,
                                          int numRows, int rowBase, float* aLDS, float* acc) {
  const int tid = threadIdx.x;
  for (int c = 0; c < 16; ++c) {
    int row = rowBase + c;
    float v = 0.0f;
    if (row < numRows) v = ldx(A, row * HDIM + tid, f32m);
    aLDS[c * HDIM + tid] = v;
  }
  __syncthreads();
#pragma unroll
  for (int r = 0; r < 16; ++r) acc[r] = 0.0f;
  for (int k0 = 0; k0 < HDIM; k0 += 4) {
    float b0 = B[(k0 + 0) * HDIM + tid];
    float b1v = B[(k0 + 1) * HDIM + tid];
    float b2v = B[(k0 + 2) * HDIM + tid];
    float b3 = B[(k0 + 3) * HDIM + tid];
#pragma unroll
    for (int r = 0; r < 16; ++r) {
      float4 a4 = *reinterpret_cast<const float4*>(&aLDS[r * HDIM + k0]);
      acc[r] += a4.x * b0;
      acc[r] += a4.y * b1v;
      acc[r] += a4.z * b2v;
      acc[r] += a4.w * b3;
    }
  }
}

// sim[row] = sum_c (Ue@M)[row][c] * S[row][c]
__global__ void __launch_bounds__(256) k_gemm_sim(const void* A, const float* B,
                                                  const void* S, const int* flags, float* sim) {
  __shared__ __align__(16) float aLDS[16 * HDIM];
  __shared__ float red[64];
  float acc[16];
  const int tid = threadIdx.x;
  const int rowBase = blockIdx.x * 16;
  const int f32m = flags[2];
  gemm_core(A, B, f32m, NROWS, rowBase, aLDS, acc);
  const int wave = tid >> 6;
#pragma unroll
  for (int r = 0; r < 16; ++r) {
    int row = rowBase + r;
    float p = 0.0f;
    if (row < NROWS) p = acc[r] * ldx(S, row * HDIM + tid, f32m);
    p += __shfl_xor(p, 1);
    p += __shfl_xor(p, 2);
    p += __shfl_xor(p, 4);
    p += __shfl_xor(p, 8);
    p += __shfl_xor(p, 16);
    p += __shfl_xor(p, 32);
    if ((tid & 63) == 0) red[wave * 16 + r] = p;
  }
  __syncthreads();
  if (tid < 16) {
    int row = rowBase + tid;
    if (row < NROWS)
      sim[row] = red[tid] + red[16 + tid] + red[32 + tid] + red[48 + tid];
  }
}

// Y[row][c] = (wsum @ W1bT)[row][c]   (wsum bf16 internal, Y f32 internal)
__global__ void __launch_bounds__(256) k_gemm_y(const __hip_bfloat16* A, const float* B,
                                                float* Y) {
  __shared__ __align__(16) float aLDS[16 * HDIM];
  float acc[16];
  const int tid = threadIdx.x;
  const int rowBase = blockIdx.x * 16;
  gemm_core((const void*)A, B, 0, NUSERS, rowBase, aLDS, acc);
#pragma unroll
  for (int r = 0; r < 16; ++r) {
    int row = rowBase + r;
    if (row < NUSERS) Y[row * HDIM + tid] = acc[r];
  }
}

// out[row][c] = relu((Ue@P)[row][c] + Y[uid[row]][c] + b1[c]), dtype per flag
__global__ void __launch_bounds__(256) k_gemm_out(const void* A, const float* B,
                                                  const int* uid, const float* Y,
                                                  const void* b1, const int* flags,
                                                  void* outv) {
  __shared__ __align__(16) float aLDS[16 * HDIM];
  float acc[16];
  const int tid = threadIdx.x;
  const int rowBase = blockIdx.x * 16;
  const int f32m = flags[2];
  gemm_core(A, B, f32m, NROWS, rowBase, aLDS, acc);
  float bias = ldx(b1, tid, f32m);
#pragma unroll
  for (int r = 0; r < 16; ++r) {
    int row = rowBase + r;
    if (row < NROWS) {
      int u = uid[row];
      float v = acc[r] + Y[u * HDIM + tid] + bias;
      if (!(v > 0.0f)) v = 0.0f;
      if (f32m != 0)
        ((float*)outv)[row * HDIM + tid] = v;
      else
        ((__hip_bfloat16*)outv)[row * HDIM + tid] = __float2bfloat16(v);
    }
  }
}

// ---- segment softmax -------------------------------------------------------
__global__ void k_segmax(const float* sim, const int* uid, int* segmaxB) {
  int i = blockIdx.x * 256 + threadIdx.x;
  if (i < NROWS) {
    float v = sim[i];
    int u = uid[i];
    if (v >= 0.0f)
      atomicMax(&segmaxB[u], __float_as_int(v));
    else
      atomicMin((unsigned int*)&segmaxB[u], __float_as_uint(v));
  }
}

__global__ void k_expdenom(const float* sim, const int* uid, const int* segmaxB,
                           float* e, float* denom) {
  int i = blockIdx.x * 256 + threadIdx.x;
  if (i < NROWS) {
    int u = uid[i];
    float m = __int_as_float(segmaxB[u]);
    float ev = __expf(sim[i] - m);
    e[i] = ev;
    atomicAdd(&denom[u], ev);
  }
}

// ---- weighted segment sum: wsum[u] = sum_i w_i * Ue[i]  (bf16 out) ---------
__global__ void k_wsum(const void* Ue, const int* offs, const int* counts,
                       const float* e, const float* denom, const int* rows,
                       const int* flags, __hip_bfloat16* wsum) {
  int u = blockIdx.x * 4 + (threadIdx.x >> 6);
  int lane = threadIdx.x & 63;
  if (u >= NUSERS) return;
  int off = offs[u], cnt = counts[u];
  int f32m = flags[2];
  float rd = 0.0f;
  if (cnt > 0) rd = 1.0f / denom[u];
  float a0 = 0.0f, a1 = 0.0f, a2 = 0.0f, a3 = 0.0f;
  for (int j = 0; j < cnt; ++j) {
    int i = rows[off + j];
    float w = e[i] * rd;
    int base = i * HDIM + lane * 4;
    a0 += w * ldx(Ue, base + 0, f32m);
    a1 += w * ldx(Ue, base + 1, f32m);
    a2 += w * ldx(Ue, base + 2, f32m);
    a3 += w * ldx(Ue, base + 3, f32m);
  }
  __hip_bfloat16* q = &wsum[u * HDIM + lane * 4];
  q[0] = __float2bfloat16(a0);
  q[1] = __float2bfloat16(a1);
  q[2] = __float2bfloat16(a2);
  q[3] = __float2bfloat16(a3);
}

extern "C" void kernel_launch(void* const* d_in, const int* in_sizes, int n_in,
                              void* d_out, int out_size, void* d_ws, size_t ws_size,
                              hipStream_t stream) {
  (void)in_sizes; (void)n_in; (void)out_size; (void)ws_size;
  const void* S  = d_in[0];
  const void* Ue = d_in[1];
  const int* uid_raw = (const int*)d_in[2];
  const void* Wq = d_in[3];
  const void* Wk = d_in[4];
  const void* Wv = d_in[5];
  const void* W1 = d_in[6];
  const void* b1 = d_in[7];

  char* w = (char*)d_ws;
  float* pM     = (float*)(w + 0);         // 256 KB
  float* pP     = (float*)(w + 262144);    // 256 KB
  float* pW1bT  = (float*)(w + 524288);    // 256 KB
  float* sim    = (float*)(w + 786432);    // N*4
  float* e      = (float*)(w + 1586432);   // N*4
  int* segmaxB  = (int*)  (w + 2386432);   // U*4
  float* denom  = (float*)(w + 2466432);   // U*4
  int* counts   = (int*)  (w + 2546432);   // U*4
  int* cursor   = (int*)  (w + 2626432);   // U*4
  int* offs     = (int*)  (w + 2706432);   // U*4
  int* rows     = (int*)  (w + 2786432);   // N*4
  int* uid      = (int*)  (w + 3586432);   // N*4
  int* flags    = (int*)  (w + 4386432);   // 256 B
  __hip_bfloat16* wsum = (__hip_bfloat16*)(w + 4386688);  // U*H*2 = 10.24 MB
  float* Y      = (float*)(w + 14626688);  // U*H*4 = 20.48 MB -> ends ~35.1 MB

  k_init<<<(NUSERS + 255) / 256, 256, 0, stream>>>(counts, cursor, denom, segmaxB, flags);
  k_dtype<<<4, 256, 0, stream>>>((const unsigned int*)S, flags);
  k_flagfin<<<1, 64, 0, stream>>>(flags);
  k_detect<<<4, 256, 0, stream>>>(uid_raw, flags);
  k_cvt<<<(NROWS + 255) / 256, 256, 0, stream>>>(uid_raw, flags, uid);
  k_pack<<<HDIM, HDIM, 0, stream>>>(Wq, Wk, Wv, W1, flags, pM, pP, pW1bT);
  k_hist<<<(NROWS + 255) / 256, 256, 0, stream>>>(uid, counts);
  k_scan<<<1, 256, 0, stream>>>(counts, offs);
  k_scatter<<<(NROWS + 255) / 256, 256, 0, stream>>>(uid, offs, cursor, rows);
  // sim = rowsum((Ue @ M) .* S)
  k_gemm_sim<<<(NROWS + 15) / 16, 256, 0, stream>>>(Ue, pM, S, flags, sim);
  k_segmax<<<(NROWS + 255) / 256, 256, 0, stream>>>(sim, uid, segmaxB);
  k_expdenom<<<(NROWS + 255) / 256, 256, 0, stream>>>(sim, uid, segmaxB, e, denom);
  k_wsum<<<(NUSERS + 3) / 4, 256, 0, stream>>>(Ue, offs, counts, e, denom, rows, flags, wsum);
  // Y = wsum @ W1b^T
  k_gemm_y<<<(NUSERS + 15) / 16, 256, 0, stream>>>(wsum, pW1bT, Y);
  // out = relu(Ue @ P + Y[uid] + b1)
  k_gemm_out<<<(NROWS + 15) / 16, 256, 0, stream>>>(Ue, pP, uid, Y, b1, flags, d_out);
}